// Round 1
// baseline (1327.916 us; speedup 1.0000x reference)
//
#include <hip/hip_runtime.h>
#include <math.h>

#define BSZ   2048
#define DIM   512
#define NMAX  256
#define MMAX  32
#define TEMPI (1.0f / 0.07f)
#define ALPHA 0.4f
#define BETA  0.2f
#define LAMBDA_BML 0.2f

__device__ __forceinline__ float wave_reduce_sum(float v) {
    #pragma unroll
    for (int off = 32; off > 0; off >>= 1)
        v += __shfl_xor(v, off, 64);
    return v;
}

__device__ __forceinline__ float dot8(float4 a0, float4 a1, float4 q0, float4 q1) {
    return a0.x * q0.x + a0.y * q0.y + a0.z * q0.z + a0.w * q0.w +
           a1.x * q1.x + a1.y * q1.y + a1.z * q1.z + a1.w * q1.w;
}

// one block per sample b; 4 waves; lane->d mapping (2 float4 per lane)
__global__ __launch_bounds__(256)
void per_sample_kernel(const float* __restrict__ q,
                       const float* __restrict__ k,
                       const float* __restrict__ k2,
                       const float* __restrict__ hn,
                       const float* __restrict__ fn,
                       const int* __restrict__ hn_counts,
                       const int* __restrict__ fn_counts,
                       float* __restrict__ ws) {
    const int b    = blockIdx.x;
    const int tid  = threadIdx.x;
    const int wave = tid >> 6;
    const int lane = tid & 63;

    __shared__ float4 sq[DIM / 4];          // 2 KB: q[b] as float4
    __shared__ float red_m[4], red_s[4], red_fn[4];
    __shared__ float red_pos, red_nb;

    const float4* q4 = (const float4*)(q + (size_t)b * DIM);
    if (tid < DIM / 4) sq[tid] = q4[tid];
    __syncthreads();

    const float4 q0 = sq[lane];
    const float4 q1 = sq[lane + 64];

    // dot(q,k) on wave 0, dot(q,k2) on wave 1 (block-uniform cheap work)
    if (wave == 0) {
        const float4* kp = (const float4*)(k + (size_t)b * DIM);
        float p = dot8(kp[lane], kp[lane + 64], q0, q1);
        p = wave_reduce_sum(p);
        if (lane == 0) red_pos = p;
    } else if (wave == 1) {
        const float4* kp = (const float4*)(k2 + (size_t)b * DIM);
        float p = dot8(kp[lane], kp[lane + 64], q0, q1);
        p = wave_reduce_sum(p);
        if (lane == 0) red_nb = p;
    }

    const int cnt  = hn_counts[b];
    const int fcnt = fn_counts[b];

    // ---- hn: online logsumexp over rows, rows strided across the 4 waves ----
    float m = -1e30f, s = 0.0f;
    const float4* hb = (const float4*)(hn + (size_t)b * NMAX * DIM);
    for (int n = wave; n < cnt; n += 4) {
        const float4* row = hb + (size_t)n * (DIM / 4);
        float4 a0 = row[lane];
        float4 a1 = row[lane + 64];
        float p = dot8(a0, a1, q0, q1);
        p = wave_reduce_sum(p);
        float l = p * TEMPI;
        if (l > m) { s = s * __expf(m - l) + 1.0f; m = l; }
        else       { s += __expf(l - m); }
    }
    if (lane == 0) { red_m[wave] = m; red_s[wave] = s; }

    // ---- fn: sum of dots; per-lane accumulate, single reduce ----
    float fp = 0.0f;
    const float4* fb = (const float4*)(fn + (size_t)b * MMAX * DIM);
    for (int mm = wave; mm < fcnt; mm += 4) {
        const float4* row = fb + (size_t)mm * (DIM / 4);
        float4 a0 = row[lane];
        float4 a1 = row[lane + 64];
        fp += dot8(a0, a1, q0, q1);
    }
    fp = wave_reduce_sum(fp);
    if (lane == 0) red_fn[wave] = fp;

    __syncthreads();

    if (tid == 0) {
        const bool valid = cnt > 0;
        const bool bv    = valid && (fcnt > 0);

        float ce_p = 0.0f, ce_n = 0.0f, bml = 0.0f;
        if (valid) {
            float M = fmaxf(fmaxf(red_m[0], red_m[1]), fmaxf(red_m[2], red_m[3]));
            float S = red_s[0] * expf(red_m[0] - M) + red_s[1] * expf(red_m[1] - M) +
                      red_s[2] * expf(red_m[2] - M) + red_s[3] * expf(red_m[3] - M);
            float lse = M + logf(S);

            float lpos = red_pos * TEMPI;
            float lnb  = red_nb * TEMPI;

            // ce(lp) = logaddexp(lp, lse) - lp, stable
            {
                float mx = fmaxf(lpos, lse);
                ce_p = mx + logf(expf(lpos - mx) + expf(lse - mx)) - lpos;
            }
            {
                float mx = fmaxf(lnb, lse);
                ce_n = mx + logf(expf(lnb - mx) + expf(lse - mx)) - lnb;
            }

            if (bv) {
                float fsum = red_fn[0] + red_fn[1] + red_fn[2] + red_fn[3];
                float sim_fn = fsum / fmaxf((float)fcnt, 1.0f);
                float delta = sim_fn - red_pos;   // sim_pos = dot(q,k) unscaled
                bml = fmaxf(delta + ALPHA, 0.0f) + fmaxf(-delta - BETA, 0.0f);
            }
        }

        ws[b]           = ce_p;                  // zero when invalid
        ws[BSZ + b]     = ce_n;
        ws[2 * BSZ + b] = bml;                   // zero when not bml_valid
        ws[3 * BSZ + b] = valid ? 1.0f : 0.0f;
        ws[4 * BSZ + b] = bv ? 1.0f : 0.0f;
    }
}

__global__ __launch_bounds__(256)
void finalize_kernel(const float* __restrict__ ws, float* __restrict__ out) {
    const int tid  = threadIdx.x;
    const int wave = tid >> 6;
    const int lane = tid & 63;

    float a0 = 0.f, a1 = 0.f, a2 = 0.f, a3 = 0.f, a4 = 0.f;
    for (int i = tid; i < BSZ; i += 256) {
        a0 += ws[i];
        a1 += ws[BSZ + i];
        a2 += ws[2 * BSZ + i];
        a3 += ws[3 * BSZ + i];
        a4 += ws[4 * BSZ + i];
    }
    a0 = wave_reduce_sum(a0);
    a1 = wave_reduce_sum(a1);
    a2 = wave_reduce_sum(a2);
    a3 = wave_reduce_sum(a3);
    a4 = wave_reduce_sum(a4);

    __shared__ float sm[5][4];
    if (lane == 0) {
        sm[0][wave] = a0; sm[1][wave] = a1; sm[2][wave] = a2;
        sm[3][wave] = a3; sm[4][wave] = a4;
    }
    __syncthreads();

    if (tid == 0) {
        float s_ce  = sm[0][0] + sm[0][1] + sm[0][2] + sm[0][3];
        float s_nb  = sm[1][0] + sm[1][1] + sm[1][2] + sm[1][3];
        float s_bml = sm[2][0] + sm[2][1] + sm[2][2] + sm[2][3];
        float s_v   = sm[3][0] + sm[3][1] + sm[3][2] + sm[3][3];
        float s_bv  = sm[4][0] + sm[4][1] + sm[4][2] + sm[4][3];

        float nv      = fmaxf(s_v, 1.0f);
        float cl      = s_ce / nv;
        float cl_nb   = s_nb / nv;
        float bml_t   = (s_bv > 0.0f) ? (LAMBDA_BML * (s_bml / s_bv)) : 0.0f;

        out[0] = cl + cl_nb + bml_t;
        out[1] = cl;
        out[2] = bml_t;
        out[3] = cl_nb;
    }
}

extern "C" void kernel_launch(void* const* d_in, const int* in_sizes, int n_in,
                              void* d_out, int out_size, void* d_ws, size_t ws_size,
                              hipStream_t stream) {
    const float* q   = (const float*)d_in[0];
    const float* k   = (const float*)d_in[1];
    const float* k2  = (const float*)d_in[2];
    const float* hn  = (const float*)d_in[3];
    const float* fn  = (const float*)d_in[4];
    const int*   hc  = (const int*)d_in[5];
    const int*   fc  = (const int*)d_in[6];
    float* out = (float*)d_out;
    float* ws  = (float*)d_ws;

    per_sample_kernel<<<BSZ, 256, 0, stream>>>(q, k, k2, hn, fn, hc, fc, ws);
    finalize_kernel<<<1, 256, 0, stream>>>(ws, out);
}